// Round 1
// baseline (1414.293 us; speedup 1.0000x reference)
//
#include <hip/hip_runtime.h>
#include <cstdint>
#include <cstddef>

// Problem constants (B=4,S=2048,H=1024,F=4096,E=8,K=2)
#define T_TOK 8192
#define HD 1024
#define FD 4096
#define NE 8
#define RCAP 17408   // 16384 pairs + 8*128 padding headroom

typedef __bf16 bf16_t;
typedef __bf16 bf16x8 __attribute__((ext_vector_type(8)));
typedef __bf16 bf16x4 __attribute__((ext_vector_type(4)));
typedef float floatx4 __attribute__((ext_vector_type(4)));

#define BM 128
#define BN 128
#define BK 64
// LDS tiles are LINEAR [128][64] (no pad): required by global_load_lds
// (DMA writes wave-uniform base + lane*16B — padding breaks lane->row map).

__device__ __forceinline__ float gelu_tanh(float x) {
    // jax.nn.gelu default (approximate=True)
    float x3 = x * x * x;
    float t = tanhf(0.7978845608028654f * (x + 0.044715f * x3));
    return 0.5f * x * (1.0f + t);
}

// async global->LDS DMA, 16B per lane. LDS dst must be wave-uniform base;
// HW adds lane*16B. Global src is per-lane.
__device__ __forceinline__ void stage16(const bf16_t* g, bf16_t* lds_base) {
    __builtin_amdgcn_global_load_lds(
        (const __attribute__((address_space(1))) void*)g,
        (__attribute__((address_space(3))) void*)lds_base,
        16, 0, 0);
}

// ---------------------------------------------------------------------------
// Transpose + fp32->bf16 convert: in [E][R][C] fp32 -> out [E][C][R] bf16
// 64x64 tile, float4 loads, bf16x4 stores. grid (C/64, R/64, E), block 256
// ---------------------------------------------------------------------------
__global__ __launch_bounds__(256) void transpose_conv_kernel(
    const float* __restrict__ in, bf16_t* __restrict__ out, int R, int C)
{
    __shared__ float tile[64][65];   // 65 pad: 2-way max on both phases
    const int e = blockIdx.z;
    const int c0 = blockIdx.x * 64;
    const int r0 = blockIdx.y * 64;
    const float* src = in + (size_t)e * R * C;
    bf16_t* dst = out + (size_t)e * R * C;

    const int tc = (threadIdx.x & 15) * 4;   // 0..60
    const int tr = threadIdx.x >> 4;         // 0..15
    #pragma unroll
    for (int p = 0; p < 4; ++p) {
        int r = tr + p * 16;
        float4 v = *(const float4*)(src + (size_t)(r0 + r) * C + c0 + tc);
        tile[r][tc]     = v.x;
        tile[r][tc + 1] = v.y;
        tile[r][tc + 2] = v.z;
        tile[r][tc + 3] = v.w;
    }
    __syncthreads();
    const int rw = (threadIdx.x & 15) * 4;   // 0..60
    const int cw = threadIdx.x >> 4;         // 0..15
    #pragma unroll
    for (int p = 0; p < 4; ++p) {
        int c = cw + p * 16;
        bf16x4 o;
        o[0] = (bf16_t)tile[rw][c];
        o[1] = (bf16_t)tile[rw + 1][c];
        o[2] = (bf16_t)tile[rw + 2][c];
        o[3] = (bf16_t)tile[rw + 3][c];
        *(bf16x4*)(dst + (size_t)(c0 + c) * R + r0 + rw) = o;
    }
}

// ---------------------------------------------------------------------------
// Router: one wave per token. fp32 logits, softmax -> top2 -> renormalize.
// grid T/4, block 256
// ---------------------------------------------------------------------------
__global__ __launch_bounds__(256) void router_kernel(
    const float* __restrict__ x, const float* __restrict__ rw,
    const float* __restrict__ rb,
    int* __restrict__ tok_e, float* __restrict__ tok_w, int* __restrict__ counts)
{
    const int t = blockIdx.x * 4 + (threadIdx.x >> 6);
    const int lane = threadIdx.x & 63;
    const float* xr = x + (size_t)t * HD;
    float acc[NE];
    #pragma unroll
    for (int e = 0; e < NE; ++e) acc[e] = 0.f;
    #pragma unroll 4
    for (int i = 0; i < HD / 64; ++i) {
        int h = lane + 64 * i;
        float xv = xr[h];
        const float4* w4 = (const float4*)(rw + (size_t)h * NE);
        float4 wa = w4[0], wb = w4[1];
        acc[0] += xv * wa.x; acc[1] += xv * wa.y;
        acc[2] += xv * wa.z; acc[3] += xv * wa.w;
        acc[4] += xv * wb.x; acc[5] += xv * wb.y;
        acc[6] += xv * wb.z; acc[7] += xv * wb.w;
    }
    #pragma unroll
    for (int s = 32; s > 0; s >>= 1)
        #pragma unroll
        for (int e = 0; e < NE; ++e)
            acc[e] += __shfl_xor(acc[e], s, 64);
    if (lane == 0) {
        float l[NE];
        #pragma unroll
        for (int e = 0; e < NE; ++e) l[e] = acc[e] + rb[e];
        int e1 = 0;
        #pragma unroll
        for (int e = 1; e < NE; ++e) if (l[e] > l[e1]) e1 = e;
        int e2 = (e1 == 0) ? 1 : 0;
        #pragma unroll
        for (int e = 0; e < NE; ++e) {
            if (e == e1 || e == e2) continue;
            if (l[e] > l[e2]) e2 = e;
        }
        float m = l[e1];
        float q1 = 1.0f;
        float q2 = expf(l[e2] - m);
        float inv = 1.0f / (q1 + q2);
        tok_e[t * 2]     = e1;
        tok_e[t * 2 + 1] = e2;
        tok_w[t * 2]     = q1 * inv;
        tok_w[t * 2 + 1] = q2 * inv;
        atomicAdd(&counts[e1], 1);
        atomicAdd(&counts[e2], 1);
    }
}

// ---------------------------------------------------------------------------
// Offsets: prefix sum of counts padded to BM. grid 1, block 64
// ---------------------------------------------------------------------------
__global__ void offsets_kernel(const int* __restrict__ counts,
                               int* __restrict__ offsets, int* __restrict__ cursors)
{
    if (threadIdx.x == 0) {
        int cum = 0;
        for (int e = 0; e < NE; ++e) {
            offsets[e] = cum;
            cursors[e] = cum;
            cum += (counts[e] + BM - 1) & ~(BM - 1);
        }
    }
}

// ---------------------------------------------------------------------------
// Gather: one wave per (token, k) pair. grid pairs/4, block 256
// ---------------------------------------------------------------------------
__global__ __launch_bounds__(256) void gather_kernel(
    const float* __restrict__ x, const int* __restrict__ tok_e,
    const float* __restrict__ tok_w, int* __restrict__ cursors,
    bf16_t* __restrict__ Xg, int* __restrict__ rows_token, float* __restrict__ rows_w)
{
    const int pair = blockIdx.x * 4 + (threadIdx.x >> 6);
    const int lane = threadIdx.x & 63;
    const int t = pair >> 1;
    int pos;
    if (lane == 0) {
        int e = tok_e[pair];
        pos = atomicAdd(&cursors[e], 1);
        rows_token[pos] = t;
        rows_w[pos] = tok_w[pair];
    }
    pos = __shfl(pos, 0, 64);
    const float4* src = (const float4*)(x + (size_t)t * HD);
    bf16_t* dst = Xg + (size_t)pos * HD;
    #pragma unroll
    for (int i = 0; i < HD / 256; ++i) {
        float4 v = src[lane + 64 * i];
        int base = (lane + 64 * i) * 4;
        bf16x4 o;
        o[0] = (bf16_t)v.x; o[1] = (bf16_t)v.y;
        o[2] = (bf16_t)v.z; o[3] = (bf16_t)v.w;
        *(bf16x4*)(dst + base) = o;
    }
}

// ---------------------------------------------------------------------------
// Shared GEMM mainloop (m97 structure): C[128x128] += A[128xK] * B^T[128xK],
// global_load_lds width-16 staging into linear LDS [128][64], 4 waves each
// 64x64 via 4x4 grid of 16x16x32 MFMAs.
// MFMA layouts (verified gfx950): A[m=lane&15][k=quad*8+j],
// B[k=quad*8+j][n=lane&15], D[row=quad*4+r][col=lane&15].
// ---------------------------------------------------------------------------
template<int KDIM>
__device__ __forceinline__ void gemm_tile(
    const bf16_t* __restrict__ aG,   // 128 rows, stride KDIM
    const bf16_t* __restrict__ bG,   // 128 rows (N-dim), stride KDIM
    bf16_t* __restrict__ As, bf16_t* __restrict__ Bs,   // [BM*BK] linear
    floatx4 acc[4][4])
{
    const int tid = threadIdx.x;
    const int lane = tid & 63;
    const int wave = tid >> 6;
    const int quad = lane >> 4;
    const int l16 = lane & 15;
    const int wm = (wave & 1) * 64;
    const int wn = (wave >> 1) * 64;
    // staging decomposition: one stage16 = 64 lanes * 16B = 8 rows of 64 bf16.
    // wave stages rows [wave*32, wave*32+32) of both A and B (4 calls each).
    const int srow = lane >> 3;          // 0..7
    const int scol = (lane & 7) * 8;     // bf16 col 0..56 (16B aligned)
    const int wrow = wave * 32;

    for (int k0 = 0; k0 < KDIM; k0 += BK) {
        #pragma unroll
        for (int p = 0; p < 4; ++p) {
            int r = wrow + p * 8;
            stage16(aG + (size_t)(r + srow) * KDIM + k0 + scol, As + r * BK);
            stage16(bG + (size_t)(r + srow) * KDIM + k0 + scol, Bs + r * BK);
        }
        __syncthreads();   // compiler emits vmcnt(0) drain before barrier
        #pragma unroll
        for (int kk = 0; kk < BK; kk += 32) {
            bf16x8 af[4], bfr[4];
            #pragma unroll
            for (int i = 0; i < 4; ++i)
                af[i] = *(const bf16x8*)(As + (wm + i * 16 + l16) * BK + kk + quad * 8);
            #pragma unroll
            for (int i = 0; i < 4; ++i)
                bfr[i] = *(const bf16x8*)(Bs + (wn + i * 16 + l16) * BK + kk + quad * 8);
            #pragma unroll
            for (int i = 0; i < 4; ++i)
                #pragma unroll
                for (int j = 0; j < 4; ++j)
                    acc[i][j] = __builtin_amdgcn_mfma_f32_16x16x32_bf16(
                        af[i], bfr[j], acc[i][j], 0, 0, 0);
        }
        __syncthreads();
    }
}

// XCD-chunked bijective swizzle (nwg % 8 == 0 for both FFN grids):
// consecutive work-ids stay on one XCD's L2 -> A-tile / B-panel reuse.
__device__ __forceinline__ int xcd_swizzle(int bid, int nwg) {
    int cpx = nwg >> 3;
    return (bid & 7) * cpx + (bid >> 3);
}

// ---------------------------------------------------------------------------
// FFN1: Hb = gelu(Xg @ w1t^T + b1), bf16 out. 1D grid 32*64*8 = 16384
// ---------------------------------------------------------------------------
__global__ __launch_bounds__(256) void ffn1_kernel(
    const bf16_t* __restrict__ Xg, const bf16_t* __restrict__ w1t,
    const float* __restrict__ b1, bf16_t* __restrict__ Hb,
    const int* __restrict__ counts, const int* __restrict__ offsets)
{
    const int nwg = (FD / BN) * (T_TOK / BM) * NE;
    int wg = xcd_swizzle(blockIdx.x, nwg);
    const int nt = wg & (FD / BN - 1);         // n fastest: A-tile reuse in L2
    int rem = wg >> 5;                          // / (FD/BN)
    const int mtile = rem & (T_TOK / BM - 1);
    const int e = rem >> 6;

    const int cnt = counts[e];
    if (mtile * BM >= cnt) return;
    const int m_base = offsets[e] + mtile * BM;
    const int n_base = nt * BN;

    __shared__ bf16_t As[BM * BK];
    __shared__ bf16_t Bs[BN * BK];
    floatx4 acc[4][4] = {};

    gemm_tile<HD>(Xg + (size_t)m_base * HD,
                  w1t + ((size_t)e * FD + n_base) * HD, As, Bs, acc);

    const int lane = threadIdx.x & 63;
    const int wave = threadIdx.x >> 6;
    const int quad = lane >> 4;
    const int l16 = lane & 15;
    const int wm = (wave & 1) * 64;
    const int wn = (wave >> 1) * 64;
    #pragma unroll
    for (int i = 0; i < 4; ++i) {
        int rl = wm + i * 16 + quad * 4;
        #pragma unroll
        for (int j = 0; j < 4; ++j) {
            int col = n_base + wn + j * 16 + l16;
            float bias = b1[e * FD + col];
            #pragma unroll
            for (int r = 0; r < 4; ++r) {
                float v = acc[i][j][r] + bias;
                Hb[(size_t)(m_base + rl + r) * FD + col] = (bf16_t)gelu_tanh(v);
            }
        }
    }
}

// ---------------------------------------------------------------------------
// FFN2: out[token] += w * (Hb @ w2t^T + b2). 1D grid 8*64*8 = 4096
// ---------------------------------------------------------------------------
__global__ __launch_bounds__(256) void ffn2_kernel(
    const bf16_t* __restrict__ Hb, const bf16_t* __restrict__ w2t,
    const float* __restrict__ b2, float* __restrict__ out,
    const int* __restrict__ counts, const int* __restrict__ offsets,
    const int* __restrict__ rows_token, const float* __restrict__ rows_w)
{
    const int nwg = (HD / BN) * (T_TOK / BM) * NE;
    int wg = xcd_swizzle(blockIdx.x, nwg);
    const int nt = wg & (HD / BN - 1);
    int rem = wg >> 3;                          // / (HD/BN)
    const int mtile = rem & (T_TOK / BM - 1);
    const int e = rem >> 6;

    const int cnt = counts[e];
    if (mtile * BM >= cnt) return;
    const int m_base = offsets[e] + mtile * BM;
    const int n_base = nt * BN;

    __shared__ bf16_t As[BM * BK];
    __shared__ bf16_t Bs[BN * BK];
    floatx4 acc[4][4] = {};

    gemm_tile<FD>(Hb + (size_t)m_base * FD,
                  w2t + ((size_t)e * HD + n_base) * FD, As, Bs, acc);

    const int lane = threadIdx.x & 63;
    const int wave = threadIdx.x >> 6;
    const int quad = lane >> 4;
    const int l16 = lane & 15;
    const int wm = (wave & 1) * 64;
    const int wn = (wave >> 1) * 64;
    const int loc_base = mtile * BM;   // m_base - offsets[e]
    #pragma unroll
    for (int i = 0; i < 4; ++i) {
        int rl = wm + i * 16 + quad * 4;
        #pragma unroll
        for (int j = 0; j < 4; ++j) {
            int col = n_base + wn + j * 16 + l16;
            float bias = b2[e * HD + col];
            #pragma unroll
            for (int r = 0; r < 4; ++r) {
                if (loc_base + rl + r < cnt) {
                    int gr = m_base + rl + r;
                    int token = rows_token[gr];
                    float wgt = rows_w[gr];
                    float v = acc[i][j][r] + bias;
                    atomicAdd(&out[(size_t)token * HD + col], wgt * v);
                }
            }
        }
    }
}

// ---------------------------------------------------------------------------
extern "C" void kernel_launch(void* const* d_in, const int* in_sizes, int n_in,
                              void* d_out, int out_size, void* d_ws, size_t ws_size,
                              hipStream_t stream)
{
    (void)in_sizes; (void)n_in; (void)ws_size;
    const float* x  = (const float*)d_in[0];   // [T, H]
    const float* w1 = (const float*)d_in[1];   // [E, H, F]
    const float* b1 = (const float*)d_in[2];   // [E, F]
    const float* w2 = (const float*)d_in[3];   // [E, F, H]
    const float* b2 = (const float*)d_in[4];   // [E, H]
    const float* rw = (const float*)d_in[5];   // [H, E]
    const float* rb = (const float*)d_in[6];   // [E]
    float* out = (float*)d_out;

    // Workspace carve-up (~313 MB total)
    char* ws = (char*)d_ws;
    size_t off = 0;
    auto alloc = [&](size_t bytes) -> void* {
        void* p = ws + off;
        off = (off + bytes + 255) & ~(size_t)255;
        return p;
    };
    int*    counts     = (int*)alloc(NE * sizeof(int));
    int*    cursors    = (int*)alloc(NE * sizeof(int));
    int*    offsets    = (int*)alloc(NE * sizeof(int));
    int*    tok_e      = (int*)alloc((size_t)T_TOK * 2 * sizeof(int));
    float*  tok_w      = (float*)alloc((size_t)T_TOK * 2 * sizeof(float));
    int*    rows_token = (int*)alloc((size_t)RCAP * sizeof(int));
    float*  rows_w     = (float*)alloc((size_t)RCAP * sizeof(float));
    bf16_t* Xg         = (bf16_t*)alloc((size_t)RCAP * HD * sizeof(bf16_t));
    bf16_t* Hb         = (bf16_t*)alloc((size_t)RCAP * FD * sizeof(bf16_t));
    bf16_t* w1t        = (bf16_t*)alloc((size_t)NE * FD * HD * sizeof(bf16_t));
    bf16_t* w2t        = (bf16_t*)alloc((size_t)NE * HD * FD * sizeof(bf16_t));

    hipMemsetAsync(counts, 0, NE * sizeof(int), stream);
    hipMemsetAsync(out, 0, (size_t)out_size * sizeof(float), stream);

    // 1. weight transpose+convert (bf16, [N][K] layout for both GEMMs)
    transpose_conv_kernel<<<dim3(FD / 64, HD / 64, NE), 256, 0, stream>>>(w1, w1t, HD, FD);
    transpose_conv_kernel<<<dim3(HD / 64, FD / 64, NE), 256, 0, stream>>>(w2, w2t, FD, HD);

    // 2. router
    router_kernel<<<dim3(T_TOK / 4), 256, 0, stream>>>(x, rw, rb, tok_e, tok_w, counts);

    // 3. offsets
    offsets_kernel<<<dim3(1), 64, 0, stream>>>(counts, offsets, cursors);

    // 4. gather
    gather_kernel<<<dim3(T_TOK * 2 / 4), 256, 0, stream>>>(
        x, tok_e, tok_w, cursors, Xg, rows_token, rows_w);

    // 5. FFN1 (+gelu) — 1D grid, XCD-chunked swizzle, early-exit on counts
    ffn1_kernel<<<dim3((FD / BN) * (T_TOK / BM) * NE), 256, 0, stream>>>(
        Xg, w1t, b1, Hb, counts, offsets);

    // 6. FFN2 (+bias, weighted scatter-add)
    ffn2_kernel<<<dim3((HD / BN) * (T_TOK / BM) * NE), 256, 0, stream>>>(
        Hb, w2t, b2, out, counts, offsets, rows_token, rows_w);
}

// Round 2
// 1331.813 us; speedup vs baseline: 1.0619x; 1.0619x over previous
//
#include <hip/hip_runtime.h>
#include <cstdint>
#include <cstddef>

// Problem constants (B=4,S=2048,H=1024,F=4096,E=8,K=2)
#define T_TOK 8192
#define HD 1024
#define FD 4096
#define NE 8
#define RCAP 17408   // 16384 pairs + 8*128 padding headroom

typedef __bf16 bf16_t;
typedef __bf16 bf16x8 __attribute__((ext_vector_type(8)));
typedef __bf16 bf16x4 __attribute__((ext_vector_type(4)));
typedef float floatx4 __attribute__((ext_vector_type(4)));

#define BM 128
#define BN 128
#define BK 64
// LDS tiles: LINEAR [128][64] destination (required by global_load_lds DMA),
// XOR-swizzled CONTENT: 16B slot col16 of row r lives at unit r*8+(col16^(r&7)).
// Achieved by pre-swizzling the per-lane GLOBAL source (rule #21 / m201):
// DMA dest stays linear, reads apply the same XOR -> both sides conflict-free.

__device__ __forceinline__ float gelu_tanh(float x) {
    // jax.nn.gelu default (approximate=True)
    float x3 = x * x * x;
    float t = tanhf(0.7978845608028654f * (x + 0.044715f * x3));
    return 0.5f * x * (1.0f + t);
}

// async global->LDS DMA, 16B per lane. LDS dst must be wave-uniform base;
// HW adds lane*16B. Global src is per-lane.
__device__ __forceinline__ void stage16(const bf16_t* g, bf16_t* lds_base) {
    __builtin_amdgcn_global_load_lds(
        (const __attribute__((address_space(1))) void*)g,
        (__attribute__((address_space(3))) void*)lds_base,
        16, 0, 0);
}

// ---------------------------------------------------------------------------
// Transpose + fp32->bf16 convert: in [E][R][C] fp32 -> out [E][C][R] bf16
// 64x64 tile, float4 loads, bf16x4 stores. grid (C/64, R/64, E), block 256
// ---------------------------------------------------------------------------
__global__ __launch_bounds__(256) void transpose_conv_kernel(
    const float* __restrict__ in, bf16_t* __restrict__ out, int R, int C)
{
    __shared__ float tile[64][65];   // 65 pad: 2-way max on both phases
    const int e = blockIdx.z;
    const int c0 = blockIdx.x * 64;
    const int r0 = blockIdx.y * 64;
    const float* src = in + (size_t)e * R * C;
    bf16_t* dst = out + (size_t)e * R * C;

    const int tc = (threadIdx.x & 15) * 4;   // 0..60
    const int tr = threadIdx.x >> 4;         // 0..15
    #pragma unroll
    for (int p = 0; p < 4; ++p) {
        int r = tr + p * 16;
        float4 v = *(const float4*)(src + (size_t)(r0 + r) * C + c0 + tc);
        tile[r][tc]     = v.x;
        tile[r][tc + 1] = v.y;
        tile[r][tc + 2] = v.z;
        tile[r][tc + 3] = v.w;
    }
    __syncthreads();
    const int rw = (threadIdx.x & 15) * 4;   // 0..60
    const int cw = threadIdx.x >> 4;         // 0..15
    #pragma unroll
    for (int p = 0; p < 4; ++p) {
        int c = cw + p * 16;
        bf16x4 o;
        o[0] = (bf16_t)tile[rw][c];
        o[1] = (bf16_t)tile[rw + 1][c];
        o[2] = (bf16_t)tile[rw + 2][c];
        o[3] = (bf16_t)tile[rw + 3][c];
        *(bf16x4*)(dst + (size_t)(c0 + c) * R + r0 + rw) = o;
    }
}

// ---------------------------------------------------------------------------
// Router: one wave per token. fp32 logits, softmax -> top2 -> renormalize.
// grid T/4, block 256
// ---------------------------------------------------------------------------
__global__ __launch_bounds__(256) void router_kernel(
    const float* __restrict__ x, const float* __restrict__ rw,
    const float* __restrict__ rb,
    int* __restrict__ tok_e, float* __restrict__ tok_w, int* __restrict__ counts)
{
    const int t = blockIdx.x * 4 + (threadIdx.x >> 6);
    const int lane = threadIdx.x & 63;
    const float* xr = x + (size_t)t * HD;
    float acc[NE];
    #pragma unroll
    for (int e = 0; e < NE; ++e) acc[e] = 0.f;
    #pragma unroll 4
    for (int i = 0; i < HD / 64; ++i) {
        int h = lane + 64 * i;
        float xv = xr[h];
        const float4* w4 = (const float4*)(rw + (size_t)h * NE);
        float4 wa = w4[0], wb = w4[1];
        acc[0] += xv * wa.x; acc[1] += xv * wa.y;
        acc[2] += xv * wa.z; acc[3] += xv * wa.w;
        acc[4] += xv * wb.x; acc[5] += xv * wb.y;
        acc[6] += xv * wb.z; acc[7] += xv * wb.w;
    }
    #pragma unroll
    for (int s = 32; s > 0; s >>= 1)
        #pragma unroll
        for (int e = 0; e < NE; ++e)
            acc[e] += __shfl_xor(acc[e], s, 64);
    if (lane == 0) {
        float l[NE];
        #pragma unroll
        for (int e = 0; e < NE; ++e) l[e] = acc[e] + rb[e];
        int e1 = 0;
        #pragma unroll
        for (int e = 1; e < NE; ++e) if (l[e] > l[e1]) e1 = e;
        int e2 = (e1 == 0) ? 1 : 0;
        #pragma unroll
        for (int e = 0; e < NE; ++e) {
            if (e == e1 || e == e2) continue;
            if (l[e] > l[e2]) e2 = e;
        }
        float m = l[e1];
        float q1 = 1.0f;
        float q2 = expf(l[e2] - m);
        float inv = 1.0f / (q1 + q2);
        tok_e[t * 2]     = e1;
        tok_e[t * 2 + 1] = e2;
        tok_w[t * 2]     = q1 * inv;
        tok_w[t * 2 + 1] = q2 * inv;
        atomicAdd(&counts[e1], 1);
        atomicAdd(&counts[e2], 1);
    }
}

// ---------------------------------------------------------------------------
// Offsets: prefix sum of counts padded to BM. grid 1, block 64
// ---------------------------------------------------------------------------
__global__ void offsets_kernel(const int* __restrict__ counts,
                               int* __restrict__ offsets, int* __restrict__ cursors)
{
    if (threadIdx.x == 0) {
        int cum = 0;
        for (int e = 0; e < NE; ++e) {
            offsets[e] = cum;
            cursors[e] = cum;
            cum += (counts[e] + BM - 1) & ~(BM - 1);
        }
    }
}

// ---------------------------------------------------------------------------
// Gather: one wave per (token, k) pair. grid pairs/4, block 256
// ---------------------------------------------------------------------------
__global__ __launch_bounds__(256) void gather_kernel(
    const float* __restrict__ x, const int* __restrict__ tok_e,
    const float* __restrict__ tok_w, int* __restrict__ cursors,
    bf16_t* __restrict__ Xg, int* __restrict__ rows_token, float* __restrict__ rows_w)
{
    const int pair = blockIdx.x * 4 + (threadIdx.x >> 6);
    const int lane = threadIdx.x & 63;
    const int t = pair >> 1;
    int pos;
    if (lane == 0) {
        int e = tok_e[pair];
        pos = atomicAdd(&cursors[e], 1);
        rows_token[pos] = t;
        rows_w[pos] = tok_w[pair];
    }
    pos = __shfl(pos, 0, 64);
    const float4* src = (const float4*)(x + (size_t)t * HD);
    bf16_t* dst = Xg + (size_t)pos * HD;
    #pragma unroll
    for (int i = 0; i < HD / 256; ++i) {
        float4 v = src[lane + 64 * i];
        int base = (lane + 64 * i) * 4;
        bf16x4 o;
        o[0] = (bf16_t)v.x; o[1] = (bf16_t)v.y;
        o[2] = (bf16_t)v.z; o[3] = (bf16_t)v.w;
        *(bf16x4*)(dst + base) = o;
    }
}

// ---------------------------------------------------------------------------
// Shared GEMM mainloop (m97 structure + both-sides XOR swizzle):
// C[128x128] += A[128xK] * B^T[128xK]. global_load_lds width-16 into linear
// LDS, source pre-swizzled so that 16B slot col16 of row r lands at unit
// r*8 + (col16 ^ (r&7)). Reads apply the same XOR -> conflict-free both ways.
// 4 waves, each 64x64 via 4x4 grid of 16x16x32 MFMAs.
// MFMA layouts (verified gfx950): A[m=lane&15][k=quad*8+j],
// B[k=quad*8+j][n=lane&15], D[row=quad*4+r][col=lane&15].
// ---------------------------------------------------------------------------
template<int KDIM>
__device__ __forceinline__ void gemm_tile(
    const bf16_t* __restrict__ aG,   // 128 rows, stride KDIM
    const bf16_t* __restrict__ bG,   // 128 rows (N-dim), stride KDIM
    bf16_t* __restrict__ As, bf16_t* __restrict__ Bs,   // [BM*BK] linear
    floatx4 acc[4][4])
{
    const int tid = threadIdx.x;
    const int lane = tid & 63;
    const int wave = tid >> 6;
    const int quad = lane >> 4;
    const int l16 = lane & 15;
    const int wm = (wave & 1) * 64;
    const int wn = (wave >> 1) * 64;
    // staging: one stage16 covers 8 rows x 8 slots. Lane lam loads global
    // (row = r0 + (lam>>3), col16 = (lam&7) ^ (lam>>3)) — bijective per
    // 8-row block since r0 % 8 == 0 -> (row&7) == lam>>3.
    const int srow = lane >> 3;                    // 0..7
    const int scol = ((lane & 7) ^ srow) << 3;     // swizzled bf16 col, 16B-aligned
    const int wrow = wave * 32;

    for (int k0 = 0; k0 < KDIM; k0 += BK) {
        #pragma unroll
        for (int p = 0; p < 4; ++p) {
            int r = wrow + p * 8;
            stage16(aG + (size_t)(r + srow) * KDIM + k0 + scol, As + r * BK);
            stage16(bG + (size_t)(r + srow) * KDIM + k0 + scol, Bs + r * BK);
        }
        __syncthreads();   // compiler emits vmcnt(0) drain before barrier
        #pragma unroll
        for (int kk = 0; kk < BK; kk += 32) {
            bf16x8 af[4], bfr[4];
            #pragma unroll
            for (int i = 0; i < 4; ++i) {
                int row = wm + i * 16 + l16;
                int slot = ((kk >> 3) + quad) ^ (row & 7);
                af[i] = *(const bf16x8*)(As + row * BK + (slot << 3));
            }
            #pragma unroll
            for (int i = 0; i < 4; ++i) {
                int row = wn + i * 16 + l16;
                int slot = ((kk >> 3) + quad) ^ (row & 7);
                bfr[i] = *(const bf16x8*)(Bs + row * BK + (slot << 3));
            }
            #pragma unroll
            for (int i = 0; i < 4; ++i)
                #pragma unroll
                for (int j = 0; j < 4; ++j)
                    acc[i][j] = __builtin_amdgcn_mfma_f32_16x16x32_bf16(
                        af[i], bfr[j], acc[i][j], 0, 0, 0);
        }
        __syncthreads();
    }
}

// XCD-chunked bijective swizzle (nwg % 8 == 0 for both FFN grids):
// consecutive work-ids stay on one XCD's L2 -> A-tile / B-panel reuse.
__device__ __forceinline__ int xcd_swizzle(int bid, int nwg) {
    int cpx = nwg >> 3;
    return (bid & 7) * cpx + (bid >> 3);
}

// ---------------------------------------------------------------------------
// FFN1: Hb = gelu(Xg @ w1t^T + b1), bf16 out. 1D grid 32*64*8 = 16384
// ---------------------------------------------------------------------------
__global__ __launch_bounds__(256) void ffn1_kernel(
    const bf16_t* __restrict__ Xg, const bf16_t* __restrict__ w1t,
    const float* __restrict__ b1, bf16_t* __restrict__ Hb,
    const int* __restrict__ counts, const int* __restrict__ offsets)
{
    const int nwg = (FD / BN) * (T_TOK / BM) * NE;
    int wg = xcd_swizzle(blockIdx.x, nwg);
    const int nt = wg & (FD / BN - 1);         // n fastest: A-tile reuse in L2
    int rem = wg >> 5;                          // / (FD/BN)
    const int mtile = rem & (T_TOK / BM - 1);
    const int e = rem >> 6;

    const int cnt = counts[e];
    if (mtile * BM >= cnt) return;
    const int m_base = offsets[e] + mtile * BM;
    const int n_base = nt * BN;

    __shared__ bf16_t As[BM * BK];
    __shared__ bf16_t Bs[BN * BK];
    floatx4 acc[4][4] = {};

    gemm_tile<HD>(Xg + (size_t)m_base * HD,
                  w1t + ((size_t)e * FD + n_base) * HD, As, Bs, acc);

    const int lane = threadIdx.x & 63;
    const int wave = threadIdx.x >> 6;
    const int quad = lane >> 4;
    const int l16 = lane & 15;
    const int wm = (wave & 1) * 64;
    const int wn = (wave >> 1) * 64;
    #pragma unroll
    for (int i = 0; i < 4; ++i) {
        int rl = wm + i * 16 + quad * 4;
        #pragma unroll
        for (int j = 0; j < 4; ++j) {
            int col = n_base + wn + j * 16 + l16;
            float bias = b1[e * FD + col];
            #pragma unroll
            for (int r = 0; r < 4; ++r) {
                float v = acc[i][j][r] + bias;
                Hb[(size_t)(m_base + rl + r) * FD + col] = (bf16_t)gelu_tanh(v);
            }
        }
    }
}

// ---------------------------------------------------------------------------
// FFN2: out[token] += w * (Hb @ w2t^T + b2). 1D grid 8*64*8 = 4096
// ---------------------------------------------------------------------------
__global__ __launch_bounds__(256) void ffn2_kernel(
    const bf16_t* __restrict__ Hb, const bf16_t* __restrict__ w2t,
    const float* __restrict__ b2, float* __restrict__ out,
    const int* __restrict__ counts, const int* __restrict__ offsets,
    const int* __restrict__ rows_token, const float* __restrict__ rows_w)
{
    const int nwg = (HD / BN) * (T_TOK / BM) * NE;
    int wg = xcd_swizzle(blockIdx.x, nwg);
    const int nt = wg & (HD / BN - 1);
    int rem = wg >> 3;                          // / (HD/BN)
    const int mtile = rem & (T_TOK / BM - 1);
    const int e = rem >> 6;

    const int cnt = counts[e];
    if (mtile * BM >= cnt) return;
    const int m_base = offsets[e] + mtile * BM;
    const int n_base = nt * BN;

    __shared__ bf16_t As[BM * BK];
    __shared__ bf16_t Bs[BN * BK];
    floatx4 acc[4][4] = {};

    gemm_tile<FD>(Hb + (size_t)m_base * FD,
                  w2t + ((size_t)e * HD + n_base) * FD, As, Bs, acc);

    const int lane = threadIdx.x & 63;
    const int wave = threadIdx.x >> 6;
    const int quad = lane >> 4;
    const int l16 = lane & 15;
    const int wm = (wave & 1) * 64;
    const int wn = (wave >> 1) * 64;
    const int loc_base = mtile * BM;   // m_base - offsets[e]
    #pragma unroll
    for (int i = 0; i < 4; ++i) {
        int rl = wm + i * 16 + quad * 4;
        #pragma unroll
        for (int j = 0; j < 4; ++j) {
            int col = n_base + wn + j * 16 + l16;
            float bias = b2[e * HD + col];
            #pragma unroll
            for (int r = 0; r < 4; ++r) {
                if (loc_base + rl + r < cnt) {
                    int gr = m_base + rl + r;
                    int token = rows_token[gr];
                    float wgt = rows_w[gr];
                    float v = acc[i][j][r] + bias;
                    atomicAdd(&out[(size_t)token * HD + col], wgt * v);
                }
            }
        }
    }
}

// ---------------------------------------------------------------------------
extern "C" void kernel_launch(void* const* d_in, const int* in_sizes, int n_in,
                              void* d_out, int out_size, void* d_ws, size_t ws_size,
                              hipStream_t stream)
{
    (void)in_sizes; (void)n_in; (void)ws_size;
    const float* x  = (const float*)d_in[0];   // [T, H]
    const float* w1 = (const float*)d_in[1];   // [E, H, F]
    const float* b1 = (const float*)d_in[2];   // [E, F]
    const float* w2 = (const float*)d_in[3];   // [E, F, H]
    const float* b2 = (const float*)d_in[4];   // [E, H]
    const float* rw = (const float*)d_in[5];   // [H, E]
    const float* rb = (const float*)d_in[6];   // [E]
    float* out = (float*)d_out;

    // Workspace carve-up (~313 MB total)
    char* ws = (char*)d_ws;
    size_t off = 0;
    auto alloc = [&](size_t bytes) -> void* {
        void* p = ws + off;
        off = (off + bytes + 255) & ~(size_t)255;
        return p;
    };
    int*    counts     = (int*)alloc(NE * sizeof(int));
    int*    cursors    = (int*)alloc(NE * sizeof(int));
    int*    offsets    = (int*)alloc(NE * sizeof(int));
    int*    tok_e      = (int*)alloc((size_t)T_TOK * 2 * sizeof(int));
    float*  tok_w      = (float*)alloc((size_t)T_TOK * 2 * sizeof(float));
    int*    rows_token = (int*)alloc((size_t)RCAP * sizeof(int));
    float*  rows_w     = (float*)alloc((size_t)RCAP * sizeof(float));
    bf16_t* Xg         = (bf16_t*)alloc((size_t)RCAP * HD * sizeof(bf16_t));
    bf16_t* Hb         = (bf16_t*)alloc((size_t)RCAP * FD * sizeof(bf16_t));
    bf16_t* w1t        = (bf16_t*)alloc((size_t)NE * FD * HD * sizeof(bf16_t));
    bf16_t* w2t        = (bf16_t*)alloc((size_t)NE * HD * FD * sizeof(bf16_t));

    hipMemsetAsync(counts, 0, NE * sizeof(int), stream);
    hipMemsetAsync(out, 0, (size_t)out_size * sizeof(float), stream);

    // 1. weight transpose+convert (bf16, [N][K] layout for both GEMMs)
    transpose_conv_kernel<<<dim3(FD / 64, HD / 64, NE), 256, 0, stream>>>(w1, w1t, HD, FD);
    transpose_conv_kernel<<<dim3(HD / 64, FD / 64, NE), 256, 0, stream>>>(w2, w2t, FD, HD);

    // 2. router
    router_kernel<<<dim3(T_TOK / 4), 256, 0, stream>>>(x, rw, rb, tok_e, tok_w, counts);

    // 3. offsets
    offsets_kernel<<<dim3(1), 64, 0, stream>>>(counts, offsets, cursors);

    // 4. gather
    gather_kernel<<<dim3(T_TOK * 2 / 4), 256, 0, stream>>>(
        x, tok_e, tok_w, cursors, Xg, rows_token, rows_w);

    // 5. FFN1 (+gelu) — 1D grid, XCD-chunked swizzle, early-exit on counts
    ffn1_kernel<<<dim3((FD / BN) * (T_TOK / BM) * NE), 256, 0, stream>>>(
        Xg, w1t, b1, Hb, counts, offsets);

    // 6. FFN2 (+bias, weighted scatter-add)
    ffn2_kernel<<<dim3((HD / BN) * (T_TOK / BM) * NE), 256, 0, stream>>>(
        Hb, w2t, b2, out, counts, offsets, rows_token, rows_w);
}

// Round 3
// 1285.616 us; speedup vs baseline: 1.1001x; 1.0359x over previous
//
#include <hip/hip_runtime.h>
#include <cstdint>
#include <cstddef>

// Problem constants (B=4,S=2048,H=1024,F=4096,E=8,K=2)
#define T_TOK 8192
#define HD 1024
#define FD 4096
#define NE 8
#define RCAP 17408   // 16384 pairs + 8*128 padding headroom

typedef __bf16 bf16_t;
typedef __bf16 bf16x8 __attribute__((ext_vector_type(8)));
typedef __bf16 bf16x4 __attribute__((ext_vector_type(4)));
typedef float floatx4 __attribute__((ext_vector_type(4)));

#define BM 128
#define BN 128
#define BK 64
// LDS tiles: double-buffered LINEAR [2][128][64] (global_load_lds DMA dest),
// XOR-swizzled CONTENT: 16B slot col16 of row r lives at unit r*8+(col16^(r&7)).
// K-loop uses counted s_waitcnt vmcnt(8): next tile's 8 DMA loads stay in
// flight across the barrier while the previous tile is consumed (T3/T4).

__device__ __forceinline__ float gelu_tanh(float x) {
    // jax.nn.gelu default (approximate=True)
    float x3 = x * x * x;
    float t = tanhf(0.7978845608028654f * (x + 0.044715f * x3));
    return 0.5f * x * (1.0f + t);
}

// async global->LDS DMA, 16B per lane. LDS dst must be wave-uniform base;
// HW adds lane*16B. Global src is per-lane.
__device__ __forceinline__ void stage16(const bf16_t* g, bf16_t* lds_base) {
    __builtin_amdgcn_global_load_lds(
        (const __attribute__((address_space(1))) void*)g,
        (__attribute__((address_space(3))) void*)lds_base,
        16, 0, 0);
}

// ---------------------------------------------------------------------------
// Transpose + fp32->bf16 convert: in [E][R][C] fp32 -> out [E][C][R] bf16
// 64x64 tile, float4 loads, bf16x4 stores. grid (C/64, R/64, E), block 256
// ---------------------------------------------------------------------------
__global__ __launch_bounds__(256) void transpose_conv_kernel(
    const float* __restrict__ in, bf16_t* __restrict__ out, int R, int C)
{
    __shared__ float tile[64][65];   // 65 pad: 2-way max on both phases
    const int e = blockIdx.z;
    const int c0 = blockIdx.x * 64;
    const int r0 = blockIdx.y * 64;
    const float* src = in + (size_t)e * R * C;
    bf16_t* dst = out + (size_t)e * R * C;

    const int tc = (threadIdx.x & 15) * 4;   // 0..60
    const int tr = threadIdx.x >> 4;         // 0..15
    #pragma unroll
    for (int p = 0; p < 4; ++p) {
        int r = tr + p * 16;
        float4 v = *(const float4*)(src + (size_t)(r0 + r) * C + c0 + tc);
        tile[r][tc]     = v.x;
        tile[r][tc + 1] = v.y;
        tile[r][tc + 2] = v.z;
        tile[r][tc + 3] = v.w;
    }
    __syncthreads();
    const int rw = (threadIdx.x & 15) * 4;   // 0..60
    const int cw = threadIdx.x >> 4;         // 0..15
    #pragma unroll
    for (int p = 0; p < 4; ++p) {
        int c = cw + p * 16;
        bf16x4 o;
        o[0] = (bf16_t)tile[rw][c];
        o[1] = (bf16_t)tile[rw + 1][c];
        o[2] = (bf16_t)tile[rw + 2][c];
        o[3] = (bf16_t)tile[rw + 3][c];
        *(bf16x4*)(dst + (size_t)(c0 + c) * R + r0 + rw) = o;
    }
}

// ---------------------------------------------------------------------------
// Router: one wave per token. fp32 logits, softmax -> top2 -> renormalize.
// grid T/4, block 256
// ---------------------------------------------------------------------------
__global__ __launch_bounds__(256) void router_kernel(
    const float* __restrict__ x, const float* __restrict__ rw,
    const float* __restrict__ rb,
    int* __restrict__ tok_e, float* __restrict__ tok_w, int* __restrict__ counts)
{
    const int t = blockIdx.x * 4 + (threadIdx.x >> 6);
    const int lane = threadIdx.x & 63;
    const float* xr = x + (size_t)t * HD;
    float acc[NE];
    #pragma unroll
    for (int e = 0; e < NE; ++e) acc[e] = 0.f;
    #pragma unroll 4
    for (int i = 0; i < HD / 64; ++i) {
        int h = lane + 64 * i;
        float xv = xr[h];
        const float4* w4 = (const float4*)(rw + (size_t)h * NE);
        float4 wa = w4[0], wb = w4[1];
        acc[0] += xv * wa.x; acc[1] += xv * wa.y;
        acc[2] += xv * wa.z; acc[3] += xv * wa.w;
        acc[4] += xv * wb.x; acc[5] += xv * wb.y;
        acc[6] += xv * wb.z; acc[7] += xv * wb.w;
    }
    #pragma unroll
    for (int s = 32; s > 0; s >>= 1)
        #pragma unroll
        for (int e = 0; e < NE; ++e)
            acc[e] += __shfl_xor(acc[e], s, 64);
    if (lane == 0) {
        float l[NE];
        #pragma unroll
        for (int e = 0; e < NE; ++e) l[e] = acc[e] + rb[e];
        int e1 = 0;
        #pragma unroll
        for (int e = 1; e < NE; ++e) if (l[e] > l[e1]) e1 = e;
        int e2 = (e1 == 0) ? 1 : 0;
        #pragma unroll
        for (int e = 0; e < NE; ++e) {
            if (e == e1 || e == e2) continue;
            if (l[e] > l[e2]) e2 = e;
        }
        float m = l[e1];
        float q1 = 1.0f;
        float q2 = expf(l[e2] - m);
        float inv = 1.0f / (q1 + q2);
        tok_e[t * 2]     = e1;
        tok_e[t * 2 + 1] = e2;
        tok_w[t * 2]     = q1 * inv;
        tok_w[t * 2 + 1] = q2 * inv;
        atomicAdd(&counts[e1], 1);
        atomicAdd(&counts[e2], 1);
    }
}

// ---------------------------------------------------------------------------
// Offsets: prefix sum of counts padded to BM. grid 1, block 64
// ---------------------------------------------------------------------------
__global__ void offsets_kernel(const int* __restrict__ counts,
                               int* __restrict__ offsets, int* __restrict__ cursors)
{
    if (threadIdx.x == 0) {
        int cum = 0;
        for (int e = 0; e < NE; ++e) {
            offsets[e] = cum;
            cursors[e] = cum;
            cum += (counts[e] + BM - 1) & ~(BM - 1);
        }
    }
}

// ---------------------------------------------------------------------------
// Gather: one wave per (token, k) pair. grid pairs/4, block 256
// ---------------------------------------------------------------------------
__global__ __launch_bounds__(256) void gather_kernel(
    const float* __restrict__ x, const int* __restrict__ tok_e,
    const float* __restrict__ tok_w, int* __restrict__ cursors,
    bf16_t* __restrict__ Xg, int* __restrict__ rows_token, float* __restrict__ rows_w)
{
    const int pair = blockIdx.x * 4 + (threadIdx.x >> 6);
    const int lane = threadIdx.x & 63;
    const int t = pair >> 1;
    int pos;
    if (lane == 0) {
        int e = tok_e[pair];
        pos = atomicAdd(&cursors[e], 1);
        rows_token[pos] = t;
        rows_w[pos] = tok_w[pair];
    }
    pos = __shfl(pos, 0, 64);
    const float4* src = (const float4*)(x + (size_t)t * HD);
    bf16_t* dst = Xg + (size_t)pos * HD;
    #pragma unroll
    for (int i = 0; i < HD / 256; ++i) {
        float4 v = src[lane + 64 * i];
        int base = (lane + 64 * i) * 4;
        bf16x4 o;
        o[0] = (bf16_t)v.x; o[1] = (bf16_t)v.y;
        o[2] = (bf16_t)v.z; o[3] = (bf16_t)v.w;
        *(bf16x4*)(dst + base) = o;
    }
}

// ---------------------------------------------------------------------------
// Shared GEMM mainloop: 2-phase double-buffered DMA pipeline (T3/T4) +
// both-sides XOR swizzle. C[128x128] += A[128xK] * B^T[128xK].
// Per K-step each wave: issue next tile's 8 global_load_lds, then
// s_waitcnt vmcnt(8) (prev tile's 8 oldest done), s_barrier, consume prev
// tile, s_barrier. Loads stay in flight across the barrier -> latency hidden
// by the compute phase instead of exposed per step.
// MFMA layouts (verified gfx950): A[m=lane&15][k=quad*8+j],
// B[k=quad*8+j][n=lane&15], D[row=quad*4+r][col=lane&15].
// ---------------------------------------------------------------------------
template<int KDIM>
__device__ __forceinline__ void gemm_tile(
    const bf16_t* __restrict__ aG,   // 128 rows, stride KDIM
    const bf16_t* __restrict__ bG,   // 128 rows (N-dim), stride KDIM
    bf16_t* __restrict__ As,         // [2][BM*BK] linear
    bf16_t* __restrict__ Bs,         // [2][BM*BK] linear
    floatx4 acc[4][4])
{
    const int tid = threadIdx.x;
    const int lane = tid & 63;
    const int wave = tid >> 6;
    const int quad = lane >> 4;
    const int l16 = lane & 15;
    const int wm = (wave & 1) * 64;
    const int wn = (wave >> 1) * 64;
    // staging: one stage16 covers 8 rows x 8 slots. Lane lam loads global
    // (row = r0 + (lam>>3), col16 = (lam&7) ^ (lam>>3)) — bijective per
    // 8-row block since r0 % 8 == 0 -> (row&7) == lam>>3.
    const int srow = lane >> 3;                    // 0..7
    const int scol = ((lane & 7) ^ srow) << 3;     // swizzled bf16 col, 16B-aligned
    const int wrow = wave * 32;

    constexpr int NT = KDIM / BK;

    auto STAGE = [&](int buf, int t) {
        bf16_t* as = As + buf * (BM * BK);
        bf16_t* bs = Bs + buf * (BM * BK);
        const size_t kofs = (size_t)t * BK;
        #pragma unroll
        for (int p = 0; p < 4; ++p) {
            int r = wrow + p * 8;
            stage16(aG + (size_t)(r + srow) * KDIM + kofs + scol, as + r * BK);
            stage16(bG + (size_t)(r + srow) * KDIM + kofs + scol, bs + r * BK);
        }
    };

    auto COMPUTE = [&](int buf) {
        const bf16_t* as = As + buf * (BM * BK);
        const bf16_t* bs = Bs + buf * (BM * BK);
        #pragma unroll
        for (int kk = 0; kk < BK; kk += 32) {
            bf16x8 af[4], bfr[4];
            #pragma unroll
            for (int i = 0; i < 4; ++i) {
                int row = wm + i * 16 + l16;
                int slot = ((kk >> 3) + quad) ^ (row & 7);
                af[i] = *(const bf16x8*)(as + row * BK + (slot << 3));
            }
            #pragma unroll
            for (int i = 0; i < 4; ++i) {
                int row = wn + i * 16 + l16;
                int slot = ((kk >> 3) + quad) ^ (row & 7);
                bfr[i] = *(const bf16x8*)(bs + row * BK + (slot << 3));
            }
            #pragma unroll
            for (int i = 0; i < 4; ++i)
                #pragma unroll
                for (int j = 0; j < 4; ++j)
                    acc[i][j] = __builtin_amdgcn_mfma_f32_16x16x32_bf16(
                        af[i], bfr[j], acc[i][j], 0, 0, 0);
        }
    };

    // prologue: tile 0 in flight
    STAGE(0, 0);
    // main loop: tiles 0 .. NT-2 consumed, tile t+1 prefetched
    for (int t = 0; t < NT - 1; ++t) {
        STAGE((t + 1) & 1, t + 1);                     // 8 loads in flight
        asm volatile("s_waitcnt vmcnt(8)" ::: "memory"); // prev tile's 8 done
        __builtin_amdgcn_sched_barrier(0);
        __builtin_amdgcn_s_barrier();                  // all waves staged t
        COMPUTE(t & 1);
        __builtin_amdgcn_s_barrier();                  // readers done before
                                                       // buf reuse next iter
    }
    // epilogue: last tile
    asm volatile("s_waitcnt vmcnt(0)" ::: "memory");
    __builtin_amdgcn_sched_barrier(0);
    __builtin_amdgcn_s_barrier();
    COMPUTE((NT - 1) & 1);
}

// XCD-chunked bijective swizzle (nwg % 8 == 0 for both FFN grids):
// consecutive work-ids stay on one XCD's L2 -> A-tile / B-panel reuse.
__device__ __forceinline__ int xcd_swizzle(int bid, int nwg) {
    int cpx = nwg >> 3;
    return (bid & 7) * cpx + (bid >> 3);
}

// ---------------------------------------------------------------------------
// FFN1: Hb = gelu(Xg @ w1t^T + b1), bf16 out. 1D grid 32*64*8 = 16384
// ---------------------------------------------------------------------------
__global__ __launch_bounds__(256) void ffn1_kernel(
    const bf16_t* __restrict__ Xg, const bf16_t* __restrict__ w1t,
    const float* __restrict__ b1, bf16_t* __restrict__ Hb,
    const int* __restrict__ counts, const int* __restrict__ offsets)
{
    const int nwg = (FD / BN) * (T_TOK / BM) * NE;
    int wg = xcd_swizzle(blockIdx.x, nwg);
    const int nt = wg & (FD / BN - 1);         // n fastest: A-tile reuse in L2
    int rem = wg >> 5;                          // / (FD/BN)
    const int mtile = rem & (T_TOK / BM - 1);
    const int e = rem >> 6;

    const int cnt = counts[e];
    if (mtile * BM >= cnt) return;
    const int m_base = offsets[e] + mtile * BM;
    const int n_base = nt * BN;

    __shared__ bf16_t As[2 * BM * BK];
    __shared__ bf16_t Bs[2 * BN * BK];
    floatx4 acc[4][4] = {};

    gemm_tile<HD>(Xg + (size_t)m_base * HD,
                  w1t + ((size_t)e * FD + n_base) * HD, As, Bs, acc);

    const int lane = threadIdx.x & 63;
    const int wave = threadIdx.x >> 6;
    const int quad = lane >> 4;
    const int l16 = lane & 15;
    const int wm = (wave & 1) * 64;
    const int wn = (wave >> 1) * 64;
    #pragma unroll
    for (int i = 0; i < 4; ++i) {
        int rl = wm + i * 16 + quad * 4;
        #pragma unroll
        for (int j = 0; j < 4; ++j) {
            int col = n_base + wn + j * 16 + l16;
            float bias = b1[e * FD + col];
            #pragma unroll
            for (int r = 0; r < 4; ++r) {
                float v = acc[i][j][r] + bias;
                Hb[(size_t)(m_base + rl + r) * FD + col] = (bf16_t)gelu_tanh(v);
            }
        }
    }
}

// ---------------------------------------------------------------------------
// FFN2: out[token] += w * (Hb @ w2t^T + b2). 1D grid 8*64*8 = 4096
// ---------------------------------------------------------------------------
__global__ __launch_bounds__(256) void ffn2_kernel(
    const bf16_t* __restrict__ Hb, const bf16_t* __restrict__ w2t,
    const float* __restrict__ b2, float* __restrict__ out,
    const int* __restrict__ counts, const int* __restrict__ offsets,
    const int* __restrict__ rows_token, const float* __restrict__ rows_w)
{
    const int nwg = (HD / BN) * (T_TOK / BM) * NE;
    int wg = xcd_swizzle(blockIdx.x, nwg);
    const int nt = wg & (HD / BN - 1);
    int rem = wg >> 3;                          // / (HD/BN)
    const int mtile = rem & (T_TOK / BM - 1);
    const int e = rem >> 6;

    const int cnt = counts[e];
    if (mtile * BM >= cnt) return;
    const int m_base = offsets[e] + mtile * BM;
    const int n_base = nt * BN;

    __shared__ bf16_t As[2 * BM * BK];
    __shared__ bf16_t Bs[2 * BN * BK];
    floatx4 acc[4][4] = {};

    gemm_tile<FD>(Hb + (size_t)m_base * FD,
                  w2t + ((size_t)e * HD + n_base) * FD, As, Bs, acc);

    const int lane = threadIdx.x & 63;
    const int wave = threadIdx.x >> 6;
    const int quad = lane >> 4;
    const int l16 = lane & 15;
    const int wm = (wave & 1) * 64;
    const int wn = (wave >> 1) * 64;
    const int loc_base = mtile * BM;   // m_base - offsets[e]
    #pragma unroll
    for (int i = 0; i < 4; ++i) {
        int rl = wm + i * 16 + quad * 4;
        #pragma unroll
        for (int j = 0; j < 4; ++j) {
            int col = n_base + wn + j * 16 + l16;
            float bias = b2[e * HD + col];
            #pragma unroll
            for (int r = 0; r < 4; ++r) {
                if (loc_base + rl + r < cnt) {
                    int gr = m_base + rl + r;
                    int token = rows_token[gr];
                    float wgt = rows_w[gr];
                    float v = acc[i][j][r] + bias;
                    atomicAdd(&out[(size_t)token * HD + col], wgt * v);
                }
            }
        }
    }
}

// ---------------------------------------------------------------------------
extern "C" void kernel_launch(void* const* d_in, const int* in_sizes, int n_in,
                              void* d_out, int out_size, void* d_ws, size_t ws_size,
                              hipStream_t stream)
{
    (void)in_sizes; (void)n_in; (void)ws_size;
    const float* x  = (const float*)d_in[0];   // [T, H]
    const float* w1 = (const float*)d_in[1];   // [E, H, F]
    const float* b1 = (const float*)d_in[2];   // [E, F]
    const float* w2 = (const float*)d_in[3];   // [E, F, H]
    const float* b2 = (const float*)d_in[4];   // [E, H]
    const float* rw = (const float*)d_in[5];   // [H, E]
    const float* rb = (const float*)d_in[6];   // [E]
    float* out = (float*)d_out;

    // Workspace carve-up (~313 MB total)
    char* ws = (char*)d_ws;
    size_t off = 0;
    auto alloc = [&](size_t bytes) -> void* {
        void* p = ws + off;
        off = (off + bytes + 255) & ~(size_t)255;
        return p;
    };
    int*    counts     = (int*)alloc(NE * sizeof(int));
    int*    cursors    = (int*)alloc(NE * sizeof(int));
    int*    offsets    = (int*)alloc(NE * sizeof(int));
    int*    tok_e      = (int*)alloc((size_t)T_TOK * 2 * sizeof(int));
    float*  tok_w      = (float*)alloc((size_t)T_TOK * 2 * sizeof(float));
    int*    rows_token = (int*)alloc((size_t)RCAP * sizeof(int));
    float*  rows_w     = (float*)alloc((size_t)RCAP * sizeof(float));
    bf16_t* Xg         = (bf16_t*)alloc((size_t)RCAP * HD * sizeof(bf16_t));
    bf16_t* Hb         = (bf16_t*)alloc((size_t)RCAP * FD * sizeof(bf16_t));
    bf16_t* w1t        = (bf16_t*)alloc((size_t)NE * FD * HD * sizeof(bf16_t));
    bf16_t* w2t        = (bf16_t*)alloc((size_t)NE * HD * FD * sizeof(bf16_t));

    hipMemsetAsync(counts, 0, NE * sizeof(int), stream);
    hipMemsetAsync(out, 0, (size_t)out_size * sizeof(float), stream);

    // 1. weight transpose+convert (bf16, [N][K] layout for both GEMMs)
    transpose_conv_kernel<<<dim3(FD / 64, HD / 64, NE), 256, 0, stream>>>(w1, w1t, HD, FD);
    transpose_conv_kernel<<<dim3(HD / 64, FD / 64, NE), 256, 0, stream>>>(w2, w2t, FD, HD);

    // 2. router
    router_kernel<<<dim3(T_TOK / 4), 256, 0, stream>>>(x, rw, rb, tok_e, tok_w, counts);

    // 3. offsets
    offsets_kernel<<<dim3(1), 64, 0, stream>>>(counts, offsets, cursors);

    // 4. gather
    gather_kernel<<<dim3(T_TOK * 2 / 4), 256, 0, stream>>>(
        x, tok_e, tok_w, cursors, Xg, rows_token, rows_w);

    // 5. FFN1 (+gelu) — 1D grid, XCD-chunked swizzle, early-exit on counts
    ffn1_kernel<<<dim3((FD / BN) * (T_TOK / BM) * NE), 256, 0, stream>>>(
        Xg, w1t, b1, Hb, counts, offsets);

    // 6. FFN2 (+bias, weighted scatter-add)
    ffn2_kernel<<<dim3((HD / BN) * (T_TOK / BM) * NE), 256, 0, stream>>>(
        Hb, w2t, b2, out, counts, offsets, rows_token, rows_w);
}